// Round 6
// baseline (6473.730 us; speedup 1.0000x reference)
//
#include <hip/hip_runtime.h>
#include <hip/hip_bf16.h>
#include <math.h>

// Problem constants (B=8, N=1024, D=256, L=4, M=1024, H=8, dh=32, K=64 clusters)
#define BN 8192           // B*N rows
#define DMODEL 256
#define FFN 1024
#define NCLUST 64

// ---------------- LayerNorm: one wave per row, float4 + shuffle reduce, no barriers ----------------
__global__ __launch_bounds__(256) void ln_wave(const float* __restrict__ x, const float* __restrict__ g,
                                               const float* __restrict__ b, float* __restrict__ y) {
    int t = threadIdx.x, w = t >> 6, l = t & 63;
    int row = blockIdx.x * 4 + w;
    const float* xr = x + (size_t)row * DMODEL;
    float4 v = *reinterpret_cast<const float4*>(xr + l * 4);
    float s = v.x + v.y + v.z + v.w;
    for (int off = 1; off < 64; off <<= 1) s += __shfl_xor(s, off);
    float mean = s * (1.0f / 256.0f);
    float4 dv = make_float4(v.x - mean, v.y - mean, v.z - mean, v.w - mean);
    float vs = dv.x * dv.x + dv.y * dv.y + dv.z * dv.z + dv.w * dv.w;
    for (int off = 1; off < 64; off <<= 1) vs += __shfl_xor(vs, off);
    float rs = rsqrtf(vs * (1.0f / 256.0f) + 1e-5f);
    float4 gg = *reinterpret_cast<const float4*>(g + l * 4);
    float4 bb = *reinterpret_cast<const float4*>(b + l * 4);
    float4 out = make_float4(dv.x * rs * gg.x + bb.x, dv.y * rs * gg.y + bb.y,
                             dv.z * rs * gg.z + bb.z, dv.w * rs * gg.w + bb.w);
    *reinterpret_cast<float4*>(y + (size_t)row * DMODEL + l * 4) = out;
}

// ---------------- Tiled GEMM v2: C[MxN] = A[MxK] @ W[KxN] (+bias)(+gelu)(+resid) ----------------
// 64 x TN tile, BK=16, 4 x (TN/16) microtile, b128 LDS fragment reads.
// k accumulation order identical to naive (k0 asc, kk asc) -> numerics preserved.
template<int TN>
__global__ __launch_bounds__(256) void gemm_t(const float* __restrict__ A, const float* __restrict__ W,
                                              const float* __restrict__ bias, const float* __restrict__ resid,
                                              float* __restrict__ C, int M, int Nn, int K, int fuse_gelu) {
    constexpr int NW = TN / 16;
    __shared__ float As[16][64];
    __shared__ float Bs[16][TN];
    int t = threadIdx.x, tx = t & 15, ty = t >> 4;
    int m0 = blockIdx.y * 64, n0 = blockIdx.x * TN;
    float acc[4][NW] = {};
    for (int k0 = 0; k0 < K; k0 += 16) {
        {   // stage A transposed: As[kk][m]
            int mr = t >> 2, kq = (t & 3) * 4;
            float4 a4 = *reinterpret_cast<const float4*>(A + (size_t)(m0 + mr) * K + k0 + kq);
            As[kq][mr] = a4.x; As[kq + 1][mr] = a4.y; As[kq + 2][mr] = a4.z; As[kq + 3][mr] = a4.w;
        }
        if (TN == 64) {   // stage B: Bs[kk][n]
            int kk = t >> 4, nq = (t & 15) * 4;
            *reinterpret_cast<float4*>(&Bs[kk][nq]) =
                *reinterpret_cast<const float4*>(W + (size_t)(k0 + kk) * Nn + n0 + nq);
        } else {
            int kk = t >> 4, nq = (t & 15) * 8;
            *reinterpret_cast<float4*>(&Bs[kk][nq]) =
                *reinterpret_cast<const float4*>(W + (size_t)(k0 + kk) * Nn + n0 + nq);
            *reinterpret_cast<float4*>(&Bs[kk][nq + 4]) =
                *reinterpret_cast<const float4*>(W + (size_t)(k0 + kk) * Nn + n0 + nq + 4);
        }
        __syncthreads();
#pragma unroll
        for (int kk = 0; kk < 16; kk++) {
            float4 a4 = *reinterpret_cast<float4*>(&As[kk][ty * 4]);
            float a[4] = {a4.x, a4.y, a4.z, a4.w};
            float bf[NW];
#pragma unroll
            for (int j = 0; j < NW; j += 4) {
                float4 b4 = *reinterpret_cast<float4*>(&Bs[kk][tx * NW + j]);
                bf[j] = b4.x; bf[j + 1] = b4.y; bf[j + 2] = b4.z; bf[j + 3] = b4.w;
            }
#pragma unroll
            for (int i = 0; i < 4; i++)
#pragma unroll
                for (int j = 0; j < NW; j++) acc[i][j] += a[i] * bf[j];
        }
        __syncthreads();
    }
#pragma unroll
    for (int i = 0; i < 4; i++) {
#pragma unroll
        for (int j = 0; j < NW; j++) {
            int row = m0 + ty * 4 + i, col = n0 + tx * NW + j;
            float v = acc[i][j];
            if (bias) v += bias[col];
            if (fuse_gelu) v = 0.5f * v * (1.0f + erff(v * 0.70710678118654752f));
            if (resid) v += resid[(size_t)row * Nn + col];
            C[(size_t)row * Nn + col] = v;
        }
    }
}

// ---------------- Attention v3: two-pass, scores in registers, 2 q-rows per wave ----------------
// Numerics: same d-ascending QK dot from LDS tile, exact max, identical exp args; only the
// PV reduction order differs (per-lane c-partials + butterfly) -> ~1e-6 perturbation.
__global__ __launch_bounds__(256, 2) void attn3(const float* __restrict__ q, const float* __restrict__ kv,
                                                float* __restrict__ o) {
    int bh = blockIdx.x, b = bh >> 3, h = bh & 7;
    int qg = blockIdx.y;                   // 128 groups of 8 rows
    int t = threadIdx.x, w = t >> 6, l = t & 63;
    int r0 = qg * 8 + w * 2;               // this wave's rows: r0, r0+1
    __shared__ float T[64][65];            // K/V tile; stride 65 -> bank (row+d)%32, 2-way max
    const float scale = 0.17677669529663687f;  // 1/sqrt(32)
    const float* kbase = kv + (size_t)b * 1024 * 512 + h * 32;
    const float* vbase = kbase + 256;
    const float* qa = q + ((size_t)(b * 1024 + r0)) * DMODEL + h * 32;
    const float* qb_ = qa + DMODEL;
    float qA[32], qB[32];
#pragma unroll
    for (int d = 0; d < 32; d++) { qA[d] = qa[d]; qB[d] = qb_[d]; }

    float sA[16], sB[16];
    for (int kt = 0; kt < 16; kt++) {
        __syncthreads();
#pragma unroll
        for (int i = 0; i < 8; i++) {
            int idx = t * 8 + i; int kr = idx >> 5, d = idx & 31;
            T[kr][d] = kbase[(size_t)(kt * 64 + kr) * 512 + d];
        }
        __syncthreads();
        float sa = 0.0f, sb = 0.0f;
#pragma unroll
        for (int d = 0; d < 32; d++) { float kk2 = T[l][d]; sa += qA[d] * kk2; sb += qB[d] * kk2; }
        sA[kt] = sa * scale; sB[kt] = sb * scale;
    }
    float mxA = -1e30f, mxB = -1e30f;
#pragma unroll
    for (int kt = 0; kt < 16; kt++) { mxA = fmaxf(mxA, sA[kt]); mxB = fmaxf(mxB, sB[kt]); }
    for (int off = 1; off < 64; off <<= 1) {
        mxA = fmaxf(mxA, __shfl_xor(mxA, off));
        mxB = fmaxf(mxB, __shfl_xor(mxB, off));
    }
    float lA = 0.0f, lB = 0.0f;
#pragma unroll
    for (int kt = 0; kt < 16; kt++) {
        sA[kt] = expf(sA[kt] - mxA); lA += sA[kt];
        sB[kt] = expf(sB[kt] - mxB); lB += sB[kt];
    }
    for (int off = 1; off < 64; off <<= 1) { lA += __shfl_xor(lA, off); lB += __shfl_xor(lB, off); }
    float invA = 1.0f / lA, invB = 1.0f / lB;

    float oA[32] = {}, oB[32] = {};
    for (int kt = 0; kt < 16; kt++) {
        __syncthreads();
#pragma unroll
        for (int i = 0; i < 8; i++) {
            int idx = t * 8 + i; int kr = idx >> 5, d = idx & 31;
            T[kr][d] = vbase[(size_t)(kt * 64 + kr) * 512 + d];
        }
        __syncthreads();
        float wa = sA[kt], wb = sB[kt];
#pragma unroll
        for (int d = 0; d < 32; d++) { float vv = T[l][d]; oA[d] += wa * vv; oB[d] += wb * vv; }
    }
    // cross-lane reduce the 32-dim partials (each lane summed its own k's)
    for (int off = 1; off < 64; off <<= 1) {
#pragma unroll
        for (int d = 0; d < 32; d++) {
            oA[d] += __shfl_xor(oA[d], off);
            oB[d] += __shfl_xor(oB[d], off);
        }
    }
    float* orow0 = o + ((size_t)(b * 1024 + r0)) * DMODEL + h * 32;
    float* orow1 = orow0 + DMODEL;
    if (l == 0) {
#pragma unroll
        for (int i = 0; i < 8; i++)
            *reinterpret_cast<float4*>(orow0 + i * 4) = make_float4(
                oA[i * 4] * invA, oA[i * 4 + 1] * invA, oA[i * 4 + 2] * invA, oA[i * 4 + 3] * invA);
    }
    if (l == 1) {
#pragma unroll
        for (int i = 0; i < 8; i++)
            *reinterpret_cast<float4*>(orow1 + i * 4) = make_float4(
                oB[i * 4] * invB, oB[i * 4 + 1] * invB, oB[i * 4 + 2] * invB, oB[i * 4 + 3] * invB);
    }
}

// ---------------- K-means (unchanged from round 5 — proven) ----------------
__global__ __launch_bounds__(256) void km_zero(float* __restrict__ sums, float* __restrict__ counts) {
    int i = blockIdx.x * 256 + threadIdx.x;
    if (i < NCLUST * DMODEL) sums[i] = 0.0f;
    if (i < NCLUST) counts[i] = 0.0f;
}

__global__ __launch_bounds__(256) void km_assign(const float* __restrict__ xf, const float* __restrict__ centers,
                                                 int* __restrict__ labels, float* __restrict__ counts, int do_counts) {
    __shared__ float CsT[DMODEL][NCLUST + 1];
    int t = threadIdx.x;
    for (int i = 0; i < 64; i++) CsT[t][i] = centers[i * DMODEL + t];
    __syncthreads();
    int lane = t & 63, wv = t >> 6;
    float csq = 0.0f;
    for (int d = 0; d < DMODEL; d++) { float c = CsT[d][lane]; csq += c * c; }
    for (int p = 0; p < 4; p++) {
        int i = blockIdx.x * 16 + wv * 4 + p;
        const float* xr = xf + (size_t)i * DMODEL;
        float dot = 0.0f, xsq = 0.0f;
        for (int d = 0; d < DMODEL; d++) { float xv = xr[d]; dot += xv * CsT[d][lane]; xsq += xv * xv; }
        float dist = xsq - 2.0f * dot + csq;
        float best = dist; int bi = lane;
        for (int off = 1; off < 64; off <<= 1) {
            float ov = __shfl_xor(best, off);
            int oi = __shfl_xor(bi, off);
            if (ov < best || (ov == best && oi < bi)) { best = ov; bi = oi; }
        }
        if (lane == 0) {
            labels[i] = bi;
            if (do_counts) atomicAdd(&counts[bi], 1.0f);
        }
    }
}

__global__ __launch_bounds__(256) void km_segsum(const float* __restrict__ xf, const int* __restrict__ labels,
                                                 float* __restrict__ sums) {
    __shared__ float lsum[NCLUST][DMODEL];
    int t = threadIdx.x;
    for (int j = 0; j < NCLUST; j++) lsum[j][t] = 0.0f;
    int base = blockIdx.x * 128;
    for (int p = 0; p < 128; p++) {
        int i = base + p;
        int lab = labels[i];
        lsum[lab][t] += xf[(size_t)i * DMODEL + t];
    }
    for (int j = 0; j < NCLUST; j++) atomicAdd(&sums[j * DMODEL + t], lsum[j][t]);
}

__global__ __launch_bounds__(256) void km_update(float* __restrict__ centers, const float* __restrict__ sums,
                                                 const float* __restrict__ counts) {
    int j = blockIdx.x, d = threadIdx.x;
    float c = counts[j];
    if (c > 0.0f) centers[j * DMODEL + d] = sums[j * DMODEL + d] / fmaxf(c, 1.0f);
}

__global__ __launch_bounds__(256) void nproj(const float* __restrict__ centers, const float* __restrict__ kW,
                                             const float* __restrict__ kb2, float* __restrict__ outc) {
    int idx = blockIdx.x * 256 + threadIdx.x;
    if (idx >= NCLUST * DMODEL) return;
    int row = idx >> 8, col = idx & 255;
    const float* cr = centers + row * DMODEL;
    float acc = 0.0f;
    for (int d = 0; d < DMODEL; d++) acc += cr[d] * kW[(size_t)d * DMODEL + col];
    outc[idx] = acc + kb2[col];
}

__global__ __launch_bounds__(256) void km_gather(const int* __restrict__ labels, const float* __restrict__ outc,
                                                 float* __restrict__ out) {
    int i = blockIdx.x, t = threadIdx.x;
    int lab = labels[i];
    out[(size_t)i * DMODEL + t] = outc[lab * DMODEL + t];
}

extern "C" void kernel_launch(void* const* d_in, const int* in_sizes, int n_in,
                              void* d_out, int out_size, void* d_ws, size_t ws_size,
                              hipStream_t stream) {
    const float* x_in  = (const float*)d_in[0];
    const float* ln1_g = (const float*)d_in[1];
    const float* ln1_b = (const float*)d_in[2];
    const float* Wq    = (const float*)d_in[3];
    const float* Wkv   = (const float*)d_in[4];
    const float* Wo    = (const float*)d_in[5];
    const float* bo    = (const float*)d_in[6];
    const float* ln2_g = (const float*)d_in[7];
    const float* ln2_b = (const float*)d_in[8];
    const float* W1    = (const float*)d_in[9];
    const float* b1    = (const float*)d_in[10];
    const float* W2    = (const float*)d_in[11];
    const float* b2    = (const float*)d_in[12];
    const float* kWp   = (const float*)d_in[13];
    const float* kbp   = (const float*)d_in[14];
    float* out = (float*)d_out;

    const size_t NEEDED = 42173440;
    if (ws_size < NEEDED) {
        hipMemsetAsync(d_out, 0, (size_t)out_size * sizeof(float), stream);
        return;
    }

    char* ws = (char*)d_ws;
    float* xf      = (float*)(ws);              //  8 MB   residual stream (mutable)
    float* xn      = (float*)(ws + 8388608);    //  8 MB   LN output; aliased as attention output
    float* ao      = xn;
    float* qb      = (float*)(ws + 16777216);   //  8 MB
    float* kvb     = (float*)(ws + 25165824);   // 16 MB
    float* hb      = (float*)(ws + 16777216);   // 16 MB   FFN hidden (qb/kvb dead by then)
    float* centers = (float*)(ws + 41943040);   // 64 KB
    float* sums    = (float*)(ws + 42008576);   // 64 KB
    float* counts  = (float*)(ws + 42074112);   // 1 KB region
    int*   labels  = (int*)  (ws + 42075136);   // 32 KB
    float* outc    = (float*)(ws + 42107904);   // 64 KB -> end 42173440

    hipMemcpyAsync(xf, x_in, (size_t)BN * DMODEL * sizeof(float), hipMemcpyDeviceToDevice, stream);

    for (int l = 0; l < 4; l++) {
        ln_wave<<<BN / 4, 256, 0, stream>>>(xf, ln1_g + l * 256, ln1_b + l * 256, xn);
        gemm_t<64><<<dim3(4, 128), 256, 0, stream>>>(xn, Wq + (size_t)l * 65536, nullptr, nullptr, qb, BN, 256, 256, 0);
        gemm_t<128><<<dim3(4, 128), 256, 0, stream>>>(xn, Wkv + (size_t)l * 131072, nullptr, nullptr, kvb, BN, 512, 256, 0);
        attn3<<<dim3(64, 128), 256, 0, stream>>>(qb, kvb, ao);   // ao == xn (xn dead now)
        gemm_t<64><<<dim3(4, 128), 256, 0, stream>>>(ao, Wo + (size_t)l * 65536, bo + l * 256, xf, xf, BN, 256, 256, 0);
        ln_wave<<<BN / 4, 256, 0, stream>>>(xf, ln2_g + l * 256, ln2_b + l * 256, xn);
        // FFN chunked over rows (2 x 4096) so hidden buffer fits in 16 MB (qb/kvb dead)
        for (int c = 0; c < 2; c++) {
            float* xnc = xn + (size_t)c * 4096 * 256;
            float* xfc = xf + (size_t)c * 4096 * 256;
            gemm_t<128><<<dim3(8, 64), 256, 0, stream>>>(xnc, W1 + (size_t)l * 262144, b1 + l * 1024, nullptr, hb, 4096, 1024, 256, 1);
            gemm_t<64><<<dim3(4, 64), 256, 0, stream>>>(hb, W2 + (size_t)l * 262144, b2 + l * 256, xfc, xfc, 4096, 256, 1024, 0);
        }
    }

    hipMemcpyAsync(centers, xf, NCLUST * DMODEL * sizeof(float), hipMemcpyDeviceToDevice, stream);
    for (int it = 0; it < 10; it++) {
        km_zero<<<64, 256, 0, stream>>>(sums, counts);
        km_assign<<<512, 256, 0, stream>>>(xf, centers, labels, counts, 1);
        km_segsum<<<64, 256, 0, stream>>>(xf, labels, sums);
        km_update<<<64, 256, 0, stream>>>(centers, sums, counts);
    }
    km_assign<<<512, 256, 0, stream>>>(xf, centers, labels, nullptr, 0);
    nproj<<<64, 256, 0, stream>>>(centers, kWp, kbp, outc);
    km_gather<<<BN, 256, 0, stream>>>(labels, outc, out);
}

// Round 7
// 3745.864 us; speedup vs baseline: 1.7282x; 1.7282x over previous
//
#include <hip/hip_runtime.h>
#include <hip/hip_bf16.h>
#include <math.h>

// Problem constants (B=8, N=1024, D=256, L=4, M=1024, H=8, dh=32, K=64 clusters)
#define BN 8192           // B*N rows
#define DMODEL 256
#define FFN 1024
#define NCLUST 64

// ---------------- LayerNorm: one wave per row, float4 + shuffle reduce, no barriers ----------------
__global__ __launch_bounds__(256) void ln_wave(const float* __restrict__ x, const float* __restrict__ g,
                                               const float* __restrict__ b, float* __restrict__ y) {
    int t = threadIdx.x, w = t >> 6, l = t & 63;
    int row = blockIdx.x * 4 + w;
    const float* xr = x + (size_t)row * DMODEL;
    float4 v = *reinterpret_cast<const float4*>(xr + l * 4);
    float s = v.x + v.y + v.z + v.w;
    for (int off = 1; off < 64; off <<= 1) s += __shfl_xor(s, off);
    float mean = s * (1.0f / 256.0f);
    float4 dv = make_float4(v.x - mean, v.y - mean, v.z - mean, v.w - mean);
    float vs = dv.x * dv.x + dv.y * dv.y + dv.z * dv.z + dv.w * dv.w;
    for (int off = 1; off < 64; off <<= 1) vs += __shfl_xor(vs, off);
    float rs = rsqrtf(vs * (1.0f / 256.0f) + 1e-5f);
    float4 gg = *reinterpret_cast<const float4*>(g + l * 4);
    float4 bb = *reinterpret_cast<const float4*>(b + l * 4);
    float4 out = make_float4(dv.x * rs * gg.x + bb.x, dv.y * rs * gg.y + bb.y,
                             dv.z * rs * gg.z + bb.z, dv.w * rs * gg.w + bb.w);
    *reinterpret_cast<float4*>(y + (size_t)row * DMODEL + l * 4) = out;
}

// ---------------- Tiled GEMM v2: C[MxN] = A[MxK] @ W[KxN] (+bias)(+gelu)(+resid) ----------------
// 64 x TN tile, BK=16, 4 x (TN/16) microtile, b128 LDS fragment reads.
// k accumulation order identical to naive (k0 asc, kk asc) -> numerics preserved.
template<int TN>
__global__ __launch_bounds__(256) void gemm_t(const float* __restrict__ A, const float* __restrict__ W,
                                              const float* __restrict__ bias, const float* __restrict__ resid,
                                              float* __restrict__ C, int M, int Nn, int K, int fuse_gelu) {
    constexpr int NW = TN / 16;
    __shared__ float As[16][64];
    __shared__ float Bs[16][TN];
    int t = threadIdx.x, tx = t & 15, ty = t >> 4;
    int m0 = blockIdx.y * 64, n0 = blockIdx.x * TN;
    float acc[4][NW] = {};
    for (int k0 = 0; k0 < K; k0 += 16) {
        {   // stage A transposed: As[kk][m]
            int mr = t >> 2, kq = (t & 3) * 4;
            float4 a4 = *reinterpret_cast<const float4*>(A + (size_t)(m0 + mr) * K + k0 + kq);
            As[kq][mr] = a4.x; As[kq + 1][mr] = a4.y; As[kq + 2][mr] = a4.z; As[kq + 3][mr] = a4.w;
        }
        if (TN == 64) {   // stage B: Bs[kk][n]
            int kk = t >> 4, nq = (t & 15) * 4;
            *reinterpret_cast<float4*>(&Bs[kk][nq]) =
                *reinterpret_cast<const float4*>(W + (size_t)(k0 + kk) * Nn + n0 + nq);
        } else {
            int kk = t >> 4, nq = (t & 15) * 8;
            *reinterpret_cast<float4*>(&Bs[kk][nq]) =
                *reinterpret_cast<const float4*>(W + (size_t)(k0 + kk) * Nn + n0 + nq);
            *reinterpret_cast<float4*>(&Bs[kk][nq + 4]) =
                *reinterpret_cast<const float4*>(W + (size_t)(k0 + kk) * Nn + n0 + nq + 4);
        }
        __syncthreads();
#pragma unroll
        for (int kk = 0; kk < 16; kk++) {
            float4 a4 = *reinterpret_cast<float4*>(&As[kk][ty * 4]);
            float a[4] = {a4.x, a4.y, a4.z, a4.w};
            float bf[NW];
#pragma unroll
            for (int j = 0; j < NW; j += 4) {
                float4 b4 = *reinterpret_cast<float4*>(&Bs[kk][tx * NW + j]);
                bf[j] = b4.x; bf[j + 1] = b4.y; bf[j + 2] = b4.z; bf[j + 3] = b4.w;
            }
#pragma unroll
            for (int i = 0; i < 4; i++)
#pragma unroll
                for (int j = 0; j < NW; j++) acc[i][j] += a[i] * bf[j];
        }
        __syncthreads();
    }
#pragma unroll
    for (int i = 0; i < 4; i++) {
#pragma unroll
        for (int j = 0; j < NW; j++) {
            int row = m0 + ty * 4 + i, col = n0 + tx * NW + j;
            float v = acc[i][j];
            if (bias) v += bias[col];
            if (fuse_gelu) v = 0.5f * v * (1.0f + erff(v * 0.70710678118654752f));
            if (resid) v += resid[(size_t)row * Nn + col];
            C[(size_t)row * Nn + col] = v;
        }
    }
}

// ---------------- Attention v2b: two-pass, one wave per q-row, full-lane PV ----------------
// Pass 1 + max + exp args bit-identical to the proven attn2; pass 2 splits columns across
// wave halves (all 64 lanes busy) and merges with one shfl_xor. Per-lane state stays small
// (qreg[32] + scalars) -- the attn3 spill disaster (160+ floats/lane) is avoided.
__global__ __launch_bounds__(256) void attn2b(const float* __restrict__ q, const float* __restrict__ kv,
                                              float* __restrict__ o) {
    int bh = blockIdx.x, b = bh >> 3, h = bh & 7;
    int qg = blockIdx.y;                 // 256 groups of 4 rows
    int t = threadIdx.x, w = t >> 6, l = t & 63;
    int n = qg * 4 + w;
    __shared__ float T[64][33];          // K/V tile; (33c+d)%32 => 2-way max (free)
    __shared__ float S[4][1024];         // per-wave score row
    const float scale = 0.17677669529663687f;  // 1/sqrt(32)
    const float* kbase = kv + (size_t)b * 1024 * 512 + h * 32;
    const float* vbase = kbase + 256;
    const float* qrow = q + ((size_t)(b * 1024 + n)) * DMODEL + h * 32;
    float qreg[32];
#pragma unroll
    for (int d = 0; d < 32; d++) qreg[d] = qrow[d];

    // pass 1: scores + per-lane max (lane l owns k = kt*64+l)
    float mx = -1e30f;
    for (int kt = 0; kt < 16; kt++) {
        __syncthreads();
#pragma unroll
        for (int i = 0; i < 8; i++) {
            int idx = t * 8 + i; int kr = idx >> 5, d = idx & 31;
            T[kr][d] = kbase[(size_t)(kt * 64 + kr) * 512 + d];
        }
        __syncthreads();
        float s = 0.0f;
#pragma unroll
        for (int d = 0; d < 32; d++) s += qreg[d] * T[l][d];
        s *= scale;
        S[w][kt * 64 + l] = s;
        mx = fmaxf(mx, s);
    }
    for (int off = 1; off < 64; off <<= 1) mx = fmaxf(mx, __shfl_xor(mx, off));

    // weights + row sum
    float lsum = 0.0f;
#pragma unroll
    for (int kt = 0; kt < 16; kt++) {
        float e = expf(S[w][kt * 64 + l] - mx);
        S[w][kt * 64 + l] = e;
        lsum += e;
    }
    for (int off = 1; off < 64; off <<= 1) lsum += __shfl_xor(lsum, off);
    float inv = 1.0f / lsum;

    // pass 2: lane l -> dim d=l&31, columns c0..c0+31 (halves split the c range)
    float od = 0.0f;
    int d = l & 31, c0 = (l >> 5) * 32;
    for (int kt = 0; kt < 16; kt++) {
        __syncthreads();
#pragma unroll
        for (int i = 0; i < 8; i++) {
            int idx = t * 8 + i; int kr = idx >> 5, dd = idx & 31;
            T[kr][dd] = vbase[(size_t)(kt * 64 + kr) * 512 + dd];
        }
        __syncthreads();
#pragma unroll 8
        for (int cc = 0; cc < 32; cc++) {
            int c = c0 + cc;
            od += S[w][kt * 64 + c] * T[c][d];
        }
    }
    od += __shfl_xor(od, 32);            // merge the two half-range partials
    if (l < 32) o[((size_t)(b * 1024 + n)) * DMODEL + h * 32 + d] = od * inv;
}

// ---------------- K-means (unchanged — proven) ----------------
__global__ __launch_bounds__(256) void km_zero(float* __restrict__ sums, float* __restrict__ counts) {
    int i = blockIdx.x * 256 + threadIdx.x;
    if (i < NCLUST * DMODEL) sums[i] = 0.0f;
    if (i < NCLUST) counts[i] = 0.0f;
}

__global__ __launch_bounds__(256) void km_assign(const float* __restrict__ xf, const float* __restrict__ centers,
                                                 int* __restrict__ labels, float* __restrict__ counts, int do_counts) {
    __shared__ float CsT[DMODEL][NCLUST + 1];
    int t = threadIdx.x;
    for (int i = 0; i < 64; i++) CsT[t][i] = centers[i * DMODEL + t];
    __syncthreads();
    int lane = t & 63, wv = t >> 6;
    float csq = 0.0f;
    for (int d = 0; d < DMODEL; d++) { float c = CsT[d][lane]; csq += c * c; }
    for (int p = 0; p < 4; p++) {
        int i = blockIdx.x * 16 + wv * 4 + p;
        const float* xr = xf + (size_t)i * DMODEL;
        float dot = 0.0f, xsq = 0.0f;
        for (int d = 0; d < DMODEL; d++) { float xv = xr[d]; dot += xv * CsT[d][lane]; xsq += xv * xv; }
        float dist = xsq - 2.0f * dot + csq;
        float best = dist; int bi = lane;
        for (int off = 1; off < 64; off <<= 1) {
            float ov = __shfl_xor(best, off);
            int oi = __shfl_xor(bi, off);
            if (ov < best || (ov == best && oi < bi)) { best = ov; bi = oi; }
        }
        if (lane == 0) {
            labels[i] = bi;
            if (do_counts) atomicAdd(&counts[bi], 1.0f);
        }
    }
}

__global__ __launch_bounds__(256) void km_segsum(const float* __restrict__ xf, const int* __restrict__ labels,
                                                 float* __restrict__ sums) {
    __shared__ float lsum[NCLUST][DMODEL];
    int t = threadIdx.x;
    for (int j = 0; j < NCLUST; j++) lsum[j][t] = 0.0f;
    int base = blockIdx.x * 128;
    for (int p = 0; p < 128; p++) {
        int i = base + p;
        int lab = labels[i];
        lsum[lab][t] += xf[(size_t)i * DMODEL + t];
    }
    for (int j = 0; j < NCLUST; j++) atomicAdd(&sums[j * DMODEL + t], lsum[j][t]);
}

__global__ __launch_bounds__(256) void km_update(float* __restrict__ centers, const float* __restrict__ sums,
                                                 const float* __restrict__ counts) {
    int j = blockIdx.x, d = threadIdx.x;
    float c = counts[j];
    if (c > 0.0f) centers[j * DMODEL + d] = sums[j * DMODEL + d] / fmaxf(c, 1.0f);
}

__global__ __launch_bounds__(256) void nproj(const float* __restrict__ centers, const float* __restrict__ kW,
                                             const float* __restrict__ kb2, float* __restrict__ outc) {
    int idx = blockIdx.x * 256 + threadIdx.x;
    if (idx >= NCLUST * DMODEL) return;
    int row = idx >> 8, col = idx & 255;
    const float* cr = centers + row * DMODEL;
    float acc = 0.0f;
    for (int d = 0; d < DMODEL; d++) acc += cr[d] * kW[(size_t)d * DMODEL + col];
    outc[idx] = acc + kb2[col];
}

__global__ __launch_bounds__(256) void km_gather(const int* __restrict__ labels, const float* __restrict__ outc,
                                                 float* __restrict__ out) {
    int i = blockIdx.x, t = threadIdx.x;
    int lab = labels[i];
    out[(size_t)i * DMODEL + t] = outc[lab * DMODEL + t];
}

extern "C" void kernel_launch(void* const* d_in, const int* in_sizes, int n_in,
                              void* d_out, int out_size, void* d_ws, size_t ws_size,
                              hipStream_t stream) {
    const float* x_in  = (const float*)d_in[0];
    const float* ln1_g = (const float*)d_in[1];
    const float* ln1_b = (const float*)d_in[2];
    const float* Wq    = (const float*)d_in[3];
    const float* Wkv   = (const float*)d_in[4];
    const float* Wo    = (const float*)d_in[5];
    const float* bo    = (const float*)d_in[6];
    const float* ln2_g = (const float*)d_in[7];
    const float* ln2_b = (const float*)d_in[8];
    const float* W1    = (const float*)d_in[9];
    const float* b1    = (const float*)d_in[10];
    const float* W2    = (const float*)d_in[11];
    const float* b2    = (const float*)d_in[12];
    const float* kWp   = (const float*)d_in[13];
    const float* kbp   = (const float*)d_in[14];
    float* out = (float*)d_out;

    const size_t NEEDED = 42173440;
    if (ws_size < NEEDED) {
        hipMemsetAsync(d_out, 0, (size_t)out_size * sizeof(float), stream);
        return;
    }

    char* ws = (char*)d_ws;
    float* xf      = (float*)(ws);              //  8 MB   residual stream (mutable)
    float* xn      = (float*)(ws + 8388608);    //  8 MB   LN output; aliased as attention output
    float* ao      = xn;
    float* qb      = (float*)(ws + 16777216);   //  8 MB
    float* kvb     = (float*)(ws + 25165824);   // 16 MB
    float* hb      = (float*)(ws + 16777216);   // 16 MB   FFN hidden (qb/kvb dead by then)
    float* centers = (float*)(ws + 41943040);   // 64 KB
    float* sums    = (float*)(ws + 42008576);   // 64 KB
    float* counts  = (float*)(ws + 42074112);   // 1 KB region
    int*   labels  = (int*)  (ws + 42075136);   // 32 KB
    float* outc    = (float*)(ws + 42107904);   // 64 KB -> end 42173440

    hipMemcpyAsync(xf, x_in, (size_t)BN * DMODEL * sizeof(float), hipMemcpyDeviceToDevice, stream);

    for (int l = 0; l < 4; l++) {
        ln_wave<<<BN / 4, 256, 0, stream>>>(xf, ln1_g + l * 256, ln1_b + l * 256, xn);
        gemm_t<64><<<dim3(4, 128), 256, 0, stream>>>(xn, Wq + (size_t)l * 65536, nullptr, nullptr, qb, BN, 256, 256, 0);
        gemm_t<128><<<dim3(4, 128), 256, 0, stream>>>(xn, Wkv + (size_t)l * 131072, nullptr, nullptr, kvb, BN, 512, 256, 0);
        attn2b<<<dim3(64, 256), 256, 0, stream>>>(qb, kvb, ao);   // ao == xn (xn dead now)
        gemm_t<64><<<dim3(4, 128), 256, 0, stream>>>(ao, Wo + (size_t)l * 65536, bo + l * 256, xf, xf, BN, 256, 256, 0);
        ln_wave<<<BN / 4, 256, 0, stream>>>(xf, ln2_g + l * 256, ln2_b + l * 256, xn);
        // FFN chunked over rows (2 x 4096) so hidden buffer fits in 16 MB (qb/kvb dead)
        for (int c = 0; c < 2; c++) {
            float* xnc = xn + (size_t)c * 4096 * 256;
            float* xfc = xf + (size_t)c * 4096 * 256;
            gemm_t<128><<<dim3(8, 64), 256, 0, stream>>>(xnc, W1 + (size_t)l * 262144, b1 + l * 1024, nullptr, hb, 4096, 1024, 256, 1);
            gemm_t<64><<<dim3(4, 64), 256, 0, stream>>>(hb, W2 + (size_t)l * 262144, b2 + l * 256, xfc, xfc, 4096, 256, 1024, 0);
        }
    }

    hipMemcpyAsync(centers, xf, NCLUST * DMODEL * sizeof(float), hipMemcpyDeviceToDevice, stream);
    for (int it = 0; it < 10; it++) {
        km_zero<<<64, 256, 0, stream>>>(sums, counts);
        km_assign<<<512, 256, 0, stream>>>(xf, centers, labels, counts, 1);
        km_segsum<<<64, 256, 0, stream>>>(xf, labels, sums);
        km_update<<<64, 256, 0, stream>>>(centers, sums, counts);
    }
    km_assign<<<512, 256, 0, stream>>>(xf, centers, labels, nullptr, 0);
    nproj<<<64, 256, 0, stream>>>(centers, kWp, kbp, outc);
    km_gather<<<BN, 256, 0, stream>>>(labels, outc, out);
}